// Round 3
// baseline (63.456 us; speedup 1.0000x reference)
//
#include <hip/hip_runtime.h>
#include <hip/hip_bf16.h>

#define BB  32
#define SS  1024
#define RR  1024
#define HID 512
#define OUTD 1024

// Layer 1: one wave per (b, j). h[b*HID+j] = relu(W1[j,:]·rep[b,:] + b1[j])
__global__ __launch_bounds__(256) void layer1_kernel(
    const float* __restrict__ rep, const float* __restrict__ W1,
    const float* __restrict__ b1, float* __restrict__ h) {
  const int gwave = (blockIdx.x * 256 + threadIdx.x) >> 6;  // 0 .. 32*512-1
  const int lane  = threadIdx.x & 63;
  const int b = gwave >> 9;          // /HID
  const int j = gwave & (HID - 1);

  const float4* w = reinterpret_cast<const float4*>(W1 + (size_t)j * RR);
  const float4* r = reinterpret_cast<const float4*>(rep + (size_t)b * RR);
  float acc = 0.f;
#pragma unroll
  for (int t = 0; t < 4; ++t) {      // 1024 floats = 256 float4 / 64 lanes
    const float4 wv = w[lane + 64 * t];
    const float4 rv = r[lane + 64 * t];
    acc += wv.x * rv.x + wv.y * rv.y + wv.z * rv.z + wv.w * rv.w;
  }
  acc += __shfl_xor(acc, 1);
  acc += __shfl_xor(acc, 2);
  acc += __shfl_xor(acc, 4);
  acc += __shfl_xor(acc, 8);
  acc += __shfl_xor(acc, 16);
  acc += __shfl_xor(acc, 32);
  if (lane == 0) h[gwave] = fmaxf(acc + b1[j], 0.f);
}

// Fused layer2 + broadcast. Block = (b, col-chunk c of 256, s-chunk q of 256).
// Grid = 32 * 4 * 4 = 512 blocks.
// Phase 1: stage h[b,:] in LDS. Phase 2: wave-per-column butterfly dot
// computes the block's 256 output columns into LDS (redundant x4 across
// s-chunks; layer2 is only 33 MFLOP total). Phase 3: stream 256 rows of
// 1 KB contiguous float4 stores.
__global__ __launch_bounds__(256) void layer2_bcast_kernel(
    const float* __restrict__ h, const float* __restrict__ W2,
    const float* __restrict__ b2, float* __restrict__ out) {
  __shared__ float s_h[HID];    // 2 KB
  __shared__ float s_o[256];    // 1 KB: this block's column chunk
  const int tid  = threadIdx.x;
  const int b    = blockIdx.x >> 4;
  const int c    = (blockIdx.x >> 2) & 3;
  const int q    = blockIdx.x & 3;
  const int wave = tid >> 6;
  const int lane = tid & 63;

  // stage h[b,:] (512 floats, one float2 per thread)
  reinterpret_cast<float2*>(s_h)[tid] =
      reinterpret_cast<const float2*>(h + (size_t)b * HID)[tid];
  __syncthreads();

  const int c0 = c << 8;
  const float4* s_h4 = reinterpret_cast<const float4*>(s_h);
#pragma unroll 4
  for (int it = 0; it < 64; ++it) {
    const int k = c0 + (it << 2) + wave;
    const float4* w = reinterpret_cast<const float4*>(W2 + (size_t)k * HID);
    const float4 w0 = w[lane], w1 = w[lane + 64];
    const float4 h0 = s_h4[lane], h1 = s_h4[lane + 64];
    float acc = w0.x * h0.x + w0.y * h0.y + w0.z * h0.z + w0.w * h0.w
              + w1.x * h1.x + w1.y * h1.y + w1.z * h1.z + w1.w * h1.w;
    acc += __shfl_xor(acc, 1);
    acc += __shfl_xor(acc, 2);
    acc += __shfl_xor(acc, 4);
    acc += __shfl_xor(acc, 8);
    acc += __shfl_xor(acc, 16);
    acc += __shfl_xor(acc, 32);
    if (lane == 0) s_o[(it << 2) + wave] = acc + b2[k];
  }
  __syncthreads();

  // broadcast: each wave writes rows s = q*256 + it*4 + wave
  const float4 v = reinterpret_cast<const float4*>(s_o)[lane];
  float4* __restrict__ out4 = reinterpret_cast<float4*>(out);
  const size_t base = ((size_t)b * SS) * (OUTD / 4) + (c << 6) + lane;
  const int s0 = q << 8;
#pragma unroll
  for (int it = 0; it < 64; ++it) {
    const int s = s0 + (it << 2) + wave;
    out4[base + (size_t)s * (OUTD / 4)] = v;
  }
}

extern "C" void kernel_launch(void* const* d_in, const int* in_sizes, int n_in,
                              void* d_out, int out_size, void* d_ws, size_t ws_size,
                              hipStream_t stream) {
  const float* rep = (const float*)d_in[0];
  // d_in[1] = size_matrix: only its shape matters (ones_like) -> unused
  const float* W1 = (const float*)d_in[2];
  const float* b1 = (const float*)d_in[3];
  const float* W2 = (const float*)d_in[4];
  const float* b2 = (const float*)d_in[5];
  float* out = (float*)d_out;
  float* h   = (float*)d_ws;                   // 32*512 floats = 64 KB

  layer1_kernel<<<BB * HID / 4, 256, 0, stream>>>(rep, W1, b1, h);
  layer2_bcast_kernel<<<BB * 4 * 4, 256, 0, stream>>>(h, W2, b2, out);
}

// Round 4
// 39.695 us; speedup vs baseline: 1.5986x; 1.5986x over previous
//
#include <hip/hip_runtime.h>
#include <hip/hip_bf16.h>

#define BB  32
#define SS  1024
#define RR  1024
#define HID 512
#define OUTD 1024

// Layer 1: one wave per (b, j). h[b*HID+j] = relu(W1[j,:]·rep[b,:] + b1[j])
__global__ __launch_bounds__(256) void layer1_kernel(
    const float* __restrict__ rep, const float* __restrict__ W1,
    const float* __restrict__ b1, float* __restrict__ h) {
  const int gwave = (blockIdx.x * 256 + threadIdx.x) >> 6;  // 0 .. 32*512-1
  const int lane  = threadIdx.x & 63;
  const int b = gwave >> 9;          // /HID
  const int j = gwave & (HID - 1);

  const float4* w = reinterpret_cast<const float4*>(W1 + (size_t)j * RR);
  const float4* r = reinterpret_cast<const float4*>(rep + (size_t)b * RR);
  float acc = 0.f;
#pragma unroll
  for (int t = 0; t < 4; ++t) {      // 1024 floats = 256 float4 / 64 lanes
    const float4 wv = w[lane + 64 * t];
    const float4 rv = r[lane + 64 * t];
    acc += wv.x * rv.x + wv.y * rv.y + wv.z * rv.z + wv.w * rv.w;
  }
  acc += __shfl_xor(acc, 1);
  acc += __shfl_xor(acc, 2);
  acc += __shfl_xor(acc, 4);
  acc += __shfl_xor(acc, 8);
  acc += __shfl_xor(acc, 16);
  acc += __shfl_xor(acc, 32);
  if (lane == 0) h[gwave] = fmaxf(acc + b1[j], 0.f);
}

// Layer 2: one wave per (b, k). out[b, 0, k] = W2[k,:]·h[b,:] + b2[k]
__global__ __launch_bounds__(256) void layer2_kernel(
    const float* __restrict__ h, const float* __restrict__ W2,
    const float* __restrict__ b2, float* __restrict__ out) {
  const int gwave = (blockIdx.x * 256 + threadIdx.x) >> 6;  // 0 .. 32*1024-1
  const int lane  = threadIdx.x & 63;
  const int b = gwave >> 10;         // /OUTD
  const int k = gwave & (OUTD - 1);

  const float4* w  = reinterpret_cast<const float4*>(W2 + (size_t)k * HID);
  const float4* hv = reinterpret_cast<const float4*>(h + (size_t)b * HID);
  float acc = 0.f;
#pragma unroll
  for (int t = 0; t < 2; ++t) {      // 512 floats = 128 float4 / 64 lanes
    const float4 wv = w[lane + 64 * t];
    const float4 xv = hv[lane + 64 * t];
    acc += wv.x * xv.x + wv.y * xv.y + wv.z * xv.z + wv.w * xv.w;
  }
  acc += __shfl_xor(acc, 1);
  acc += __shfl_xor(acc, 2);
  acc += __shfl_xor(acc, 4);
  acc += __shfl_xor(acc, 8);
  acc += __shfl_xor(acc, 16);
  acc += __shfl_xor(acc, 32);
  if (lane == 0) out[(size_t)b * SS * OUTD + k] = acc + b2[k];
}

// Broadcast: block = (b, s-chunk of 8 rows). Grid = 32*128 = 4096 blocks.
// Each thread reads one float4 of out[b,0,:] (L2-hot, 128 KB total) and
// stores it to 8 rows; each row is a contiguous 4 KB block store.
// Rows s>=1 only (row 0 already holds the value) -> no read/write race.
__global__ __launch_bounds__(256) void bcast_kernel(float* __restrict__ out) {
  const int b  = blockIdx.x >> 7;          // 0..31
  const int sc = blockIdx.x & 127;         // 0..127 (8 rows each)
  float4* __restrict__ base =
      reinterpret_cast<float4*>(out) + (size_t)b * SS * (OUTD / 4);
  const float4 v = base[threadIdx.x];      // source row s=0
  const int s0 = sc << 3;
#pragma unroll
  for (int i = 0; i < 8; ++i) {
    const int s = s0 + i;
    if (s != 0) base[(size_t)s * (OUTD / 4) + threadIdx.x] = v;
  }
}

extern "C" void kernel_launch(void* const* d_in, const int* in_sizes, int n_in,
                              void* d_out, int out_size, void* d_ws, size_t ws_size,
                              hipStream_t stream) {
  const float* rep = (const float*)d_in[0];
  // d_in[1] = size_matrix: only its shape matters (ones_like) -> unused
  const float* W1 = (const float*)d_in[2];
  const float* b1 = (const float*)d_in[3];
  const float* W2 = (const float*)d_in[4];
  const float* b2 = (const float*)d_in[5];
  float* out = (float*)d_out;
  float* h   = (float*)d_ws;                   // 32*512 floats = 64 KB

  layer1_kernel<<<BB * HID / 4, 256, 0, stream>>>(rep, W1, b1, h);
  layer2_kernel<<<BB * OUTD / 4, 256, 0, stream>>>(h, W2, b2, out);
  bcast_kernel<<<BB * 128, 256, 0, stream>>>(out);
}

// Round 6
// 35.803 us; speedup vs baseline: 1.7724x; 1.1087x over previous
//
#include <hip/hip_runtime.h>
#include <hip/hip_bf16.h>

#define BB   32
#define SS   1024
#define RR   1024
#define HID  512
#define OUTD 1024

// Layer 1: one wave per (4-j tile, 2-batch tile). 16-lane group g owns row
// j = jq*4+g; lanes l16 each accumulate 16 float4 of the 1024-dot; W1 row is
// read ONCE per wave and reused for both batches. 4-level group reduce.
// Grid: 128 j-quads * 16 b-pairs = 2048 one-wave blocks.
__global__ __launch_bounds__(64) void layer1_kernel(
    const float* __restrict__ rep, const float* __restrict__ W1,
    const float* __restrict__ b1, float* __restrict__ h) {
  const int lane = threadIdx.x;
  const int g    = lane >> 4;              // 0..3 -> row within tile
  const int l16  = lane & 15;
  const int jq   = blockIdx.x >> 4;        // 0..127
  const int b0   = (blockIdx.x & 15) << 1; // 0,2,..,30
  const int j    = (jq << 2) + g;

  const float4* w4 = reinterpret_cast<const float4*>(W1 + (size_t)j * RR);
  const float4* r0 = reinterpret_cast<const float4*>(rep + (size_t)b0 * RR);
  const float4* r1 = reinterpret_cast<const float4*>(rep + (size_t)(b0 + 1) * RR);
  float a0 = 0.f, a1 = 0.f;
#pragma unroll
  for (int t = 0; t < 16; ++t) {           // 256 float4 / 16 lanes
    const float4 w = w4[l16 + 16 * t];
    const float4 x = r0[l16 + 16 * t];
    const float4 y = r1[l16 + 16 * t];
    a0 += w.x * x.x + w.y * x.y + w.z * x.z + w.w * x.w;
    a1 += w.x * y.x + w.y * y.y + w.z * y.z + w.w * y.w;
  }
#pragma unroll
  for (int m = 1; m <= 8; m <<= 1) {
    a0 += __shfl_xor(a0, m);
    a1 += __shfl_xor(a1, m);
  }
  if (l16 == 0) {
    const float bb = b1[j];
    h[(size_t)b0 * HID + j]       = fmaxf(a0 + bb, 0.f);
    h[(size_t)(b0 + 1) * HID + j] = fmaxf(a1 + bb, 0.f);
  }
}

// Layer 2: one wave per (4-k tile, 2-batch tile). Same scheme, 512-dot
// (8 float4 per lane). Writes out[b, 0, k].
// Grid: 256 k-quads * 16 b-pairs = 4096 one-wave blocks.
__global__ __launch_bounds__(64) void layer2_kernel(
    const float* __restrict__ h, const float* __restrict__ W2,
    const float* __restrict__ b2, float* __restrict__ out) {
  const int lane = threadIdx.x;
  const int g    = lane >> 4;
  const int l16  = lane & 15;
  const int kq   = blockIdx.x >> 4;        // 0..255
  const int b0   = (blockIdx.x & 15) << 1;
  const int k    = (kq << 2) + g;

  const float4* w4 = reinterpret_cast<const float4*>(W2 + (size_t)k * HID);
  const float4* h0 = reinterpret_cast<const float4*>(h + (size_t)b0 * HID);
  const float4* h1 = reinterpret_cast<const float4*>(h + (size_t)(b0 + 1) * HID);
  float a0 = 0.f, a1 = 0.f;
#pragma unroll
  for (int t = 0; t < 8; ++t) {            // 128 float4 / 16 lanes
    const float4 w = w4[l16 + 16 * t];
    const float4 x = h0[l16 + 16 * t];
    const float4 y = h1[l16 + 16 * t];
    a0 += w.x * x.x + w.y * x.y + w.z * x.z + w.w * x.w;
    a1 += w.x * y.x + w.y * y.y + w.z * y.z + w.w * y.w;
  }
#pragma unroll
  for (int m = 1; m <= 8; m <<= 1) {
    a0 += __shfl_xor(a0, m);
    a1 += __shfl_xor(a1, m);
  }
  if (l16 == 0) {
    const float bb = b2[k];
    out[(size_t)b0 * SS * OUTD + k]       = a0 + bb;
    out[(size_t)(b0 + 1) * SS * OUTD + k] = a1 + bb;
  }
}

// Broadcast: block = (b, s-chunk of 8 rows). Grid = 32*128 = 4096 blocks.
// Each thread reads one float4 of out[b,0,:] (L2-hot) and stores it to 8
// rows; each row is a contiguous 4 KB block store. Rows s>=1 only.
__global__ __launch_bounds__(256) void bcast_kernel(float* __restrict__ out) {
  const int b  = blockIdx.x >> 7;          // 0..31
  const int sc = blockIdx.x & 127;         // 0..127
  float4* __restrict__ base =
      reinterpret_cast<float4*>(out) + (size_t)b * SS * (OUTD / 4);
  const float4 v = base[threadIdx.x];      // source row s=0
  const int s0 = sc << 3;
#pragma unroll
  for (int i = 0; i < 8; ++i) {
    const int s = s0 + i;
    if (s != 0) base[(size_t)s * (OUTD / 4) + threadIdx.x] = v;
  }
}

extern "C" void kernel_launch(void* const* d_in, const int* in_sizes, int n_in,
                              void* d_out, int out_size, void* d_ws, size_t ws_size,
                              hipStream_t stream) {
  const float* rep = (const float*)d_in[0];
  // d_in[1] = size_matrix: only its shape matters (ones_like) -> unused
  const float* W1 = (const float*)d_in[2];
  const float* b1 = (const float*)d_in[3];
  const float* W2 = (const float*)d_in[4];
  const float* b2 = (const float*)d_in[5];
  float* out = (float*)d_out;
  float* h   = (float*)d_ws;               // 32*512 floats = 64 KB

  layer1_kernel<<<2048, 64, 0, stream>>>(rep, W1, b1, h);
  layer2_kernel<<<4096, 64, 0, stream>>>(h, W2, b2, out);
  bcast_kernel<<<BB * 128, 256, 0, stream>>>(out);
}